// Round 5
// baseline (129.200 us; speedup 1.0000x reference)
//
#include <hip/hip_runtime.h>
#include <hip/hip_bf16.h>

typedef __bf16 bf16x2_t __attribute__((ext_vector_type(2)));
typedef __bf16 bf16x8_t __attribute__((ext_vector_type(8)));
typedef float f32x4 __attribute__((ext_vector_type(4)));

#define BATCH   8
#define LENGTH  4096
#define KHALF   128
#define MTOT    (BATCH*LENGTH)
#define NCHUNK  128
#define LC      32

// 16B-chunk XOR swizzle: chunk index ^ (row & 7). Keeps b128 frag reads and
// bf16x2 scan accesses at <=2-way bank conflict with ZERO padding.
#define SWZ(ch, row) ((ch) ^ ((row) & 7))

// ---------------- transpose B, C to bf16 ----------------
__global__ __launch_bounds__(256) void transpose_bc(
    const float* __restrict__ Bsrc, const float* __restrict__ Csrc,
    __bf16* __restrict__ BT, __bf16* __restrict__ CT) {
  const float* src = blockIdx.y ? Csrc : Bsrc;
  __bf16* dst      = blockIdx.y ? CT   : BT;
  int n  = blockIdx.x;
  int kk = threadIdx.x;
  dst[n * 256 + kk] = (__bf16)src[kk * 256 + n];
}

// ---------------- Kernel 1: chunk partials P only (no uB write) ----------------
// 64x256 panel per block: stage u -> bf16 LDS, MFMA uB tile, stash, scan -> P.
__global__ __launch_bounds__(256, 2) void gemm_p(
    const float* __restrict__ u, const __bf16* __restrict__ BT,
    const float* __restrict__ Aarr, float2* __restrict__ P) {
  __shared__ __align__(16) __bf16 sT[64 * 256];   // 32 KB

  const int tid  = threadIdx.x;
  const int lane = tid & 63;
  const int wave = tid >> 6;
  const int m_l  = lane & 15, quad = lane >> 4;
  const int m0   = blockIdx.x * 64;
  const int b    = m0 >> 12;
  const int t0   = m0 & 4095;

  // stage u (fp32 -> bf16), swizzled 16B chunks
#pragma unroll
  for (int i = 0; i < 8; ++i) {
    int s   = tid + i * 256;
    int row = s >> 5, ch = s & 31;
    const float4* g = (const float4*)(u + (size_t)(m0 + row) * 256 + ch * 8);
    float4 a = g[0], c = g[1];
    bf16x8_t v;
    v[0]=(__bf16)a.x; v[1]=(__bf16)a.y; v[2]=(__bf16)a.z; v[3]=(__bf16)a.w;
    v[4]=(__bf16)c.x; v[5]=(__bf16)c.y; v[6]=(__bf16)c.z; v[7]=(__bf16)c.w;
    *(bf16x8_t*)&sT[row * 256 + SWZ(ch, row) * 8] = v;
  }
  __syncthreads();

  f32x4 acc[4][4];
#pragma unroll
  for (int mi = 0; mi < 4; ++mi)
#pragma unroll
    for (int ni = 0; ni < 4; ++ni)
#pragma unroll
      for (int r = 0; r < 4; ++r) acc[mi][ni][r] = 0.f;

#pragma unroll
  for (int kc8 = 0; kc8 < 8; ++kc8) {     // barrier-free K-loop
    bf16x8_t af[4], bfr[4];
#pragma unroll
    for (int mi = 0; mi < 4; ++mi) {
      int row = mi * 16 + m_l;
      int c   = kc8 * 4 + quad;
      af[mi] = *(const bf16x8_t*)&sT[row * 256 + SWZ(c, row) * 8];
    }
#pragma unroll
    for (int ni = 0; ni < 4; ++ni) {
      int n = wave * 64 + ni * 16 + m_l;
      bfr[ni] = *(const bf16x8_t*)(BT + (size_t)n * 256 + kc8 * 32 + quad * 8);
    }
#pragma unroll
    for (int mi = 0; mi < 4; ++mi)
#pragma unroll
      for (int ni = 0; ni < 4; ++ni)
        acc[mi][ni] = __builtin_amdgcn_mfma_f32_16x16x32_bf16(af[mi], bfr[ni], acc[mi][ni], 0, 0, 0);
  }
  __syncthreads();

  // stash bf16 uB tile (swizzled)
#pragma unroll
  for (int mi = 0; mi < 4; ++mi)
#pragma unroll
    for (int ni = 0; ni < 4; ++ni)
#pragma unroll
      for (int r = 0; r < 4; ++r) {
        int row = mi * 16 + quad * 4 + r;
        int col = wave * 64 + ni * 16 + m_l;
        sT[row * 256 + SWZ(col >> 3, row) * 8 + (col & 7)] = (__bf16)acc[mi][ni][r];
      }
  __syncthreads();

  // chunk-partial scans: 2 chunks x 128 k, one per thread
  {
    int k   = tid & 127;
    int chl = tid >> 7;
    float cc = Aarr[4 * k], sv = Aarr[4 * k + 1];
    float hr = 0.f, hi = 0.f;
#pragma unroll 8
    for (int j = 0; j < LC; ++j) {
      int row = chl * 32 + j;
      bf16x2_t v2 = *(const bf16x2_t*)&sT[row * 256 + SWZ(k >> 2, row) * 8 + ((2 * k) & 7)];
      float t = fmaf(hr, cc, fmaf(-hi, sv, (float)v2[0]));
      hi      = fmaf(hr, sv, fmaf( hi, cc, (float)v2[1]));
      hr = t;
    }
    int chg = (t0 >> 5) + chl;
    P[((size_t)b * NCHUNK + chg) * KHALF + k] = make_float2(hr, hi);
  }
}

// ---------------- Kernel 2: recompute uB tile, per-block carry from P, replay, y = X @ C ----
__global__ __launch_bounds__(256, 2) void ssm_out(
    const float* __restrict__ u, const __bf16* __restrict__ BT,
    const __bf16* __restrict__ CT, const float* __restrict__ Aarr,
    const float* __restrict__ x0, const float2* __restrict__ P,
    float* __restrict__ state_out, float* __restrict__ Y) {
  __shared__ __align__(16) __bf16 sT[64 * 256];   // 32 KB

  const int tid  = threadIdx.x;
  const int lane = tid & 63;
  const int wave = tid >> 6;
  const int m_l  = lane & 15, quad = lane >> 4;
  const int m0   = blockIdx.x * 64;
  const int b    = m0 >> 12;
  const int t0   = m0 & 4095;

  // stage u (fp32 -> bf16), swizzled — u is L3-resident from kernel 1
#pragma unroll
  for (int i = 0; i < 8; ++i) {
    int s   = tid + i * 256;
    int row = s >> 5, ch = s & 31;
    const float4* g = (const float4*)(u + (size_t)(m0 + row) * 256 + ch * 8);
    float4 a = g[0], c = g[1];
    bf16x8_t v;
    v[0]=(__bf16)a.x; v[1]=(__bf16)a.y; v[2]=(__bf16)a.z; v[3]=(__bf16)a.w;
    v[4]=(__bf16)c.x; v[5]=(__bf16)c.y; v[6]=(__bf16)c.z; v[7]=(__bf16)c.w;
    *(bf16x8_t*)&sT[row * 256 + SWZ(ch, row) * 8] = v;
  }

  // per-block carry-in: h = x0 advanced through chunks [0, chg) with w32
  const int k   = tid & 127;
  const int chl = tid >> 7;
  const int chg = (t0 >> 5) + chl;
  const float cc = Aarr[4 * k], sv = Aarr[4 * k + 1];
  float carry_r, carry_i;
  {
    float wr = cc, wi = sv;                 // w^32 via 5 squarings
#pragma unroll
    for (int i = 0; i < 5; ++i) { float nr = wr*wr - wi*wi; wi = 2.f*wr*wi; wr = nr; }
    float hr = x0[b * 256 + 2 * k], hi = x0[b * 256 + 2 * k + 1];
    const float2* pp = P + (size_t)b * NCHUNK * KHALF + k;
#pragma unroll 4
    for (int ch = 0; ch < chg; ++ch) {
      float2 pv = pp[(size_t)ch * KHALF];
      float t = fmaf(hr, wr, fmaf(-hi, wi, pv.x));
      hi      = fmaf(hr, wi, fmaf( hi, wr, pv.y));
      hr = t;
    }
    carry_r = hr; carry_i = hi;
  }
  __syncthreads();

  // MFMA: uB tile = u @ B
  f32x4 acc[4][4];
#pragma unroll
  for (int mi = 0; mi < 4; ++mi)
#pragma unroll
    for (int ni = 0; ni < 4; ++ni)
#pragma unroll
      for (int r = 0; r < 4; ++r) acc[mi][ni][r] = 0.f;

#pragma unroll
  for (int kc8 = 0; kc8 < 8; ++kc8) {
    bf16x8_t af[4], bfr[4];
#pragma unroll
    for (int mi = 0; mi < 4; ++mi) {
      int row = mi * 16 + m_l;
      int c   = kc8 * 4 + quad;
      af[mi] = *(const bf16x8_t*)&sT[row * 256 + SWZ(c, row) * 8];
    }
#pragma unroll
    for (int ni = 0; ni < 4; ++ni) {
      int n = wave * 64 + ni * 16 + m_l;
      bfr[ni] = *(const bf16x8_t*)(BT + (size_t)n * 256 + kc8 * 32 + quad * 8);
    }
#pragma unroll
    for (int mi = 0; mi < 4; ++mi)
#pragma unroll
      for (int ni = 0; ni < 4; ++ni)
        acc[mi][ni] = __builtin_amdgcn_mfma_f32_16x16x32_bf16(af[mi], bfr[ni], acc[mi][ni], 0, 0, 0);
  }
  __syncthreads();

  // stash bf16 uB tile (swizzled)
#pragma unroll
  for (int mi = 0; mi < 4; ++mi)
#pragma unroll
    for (int ni = 0; ni < 4; ++ni)
#pragma unroll
      for (int r = 0; r < 4; ++r) {
        int row = mi * 16 + quad * 4 + r;
        int col = wave * 64 + ni * 16 + m_l;
        sT[row * 256 + SWZ(col >> 3, row) * 8 + (col & 7)] = (__bf16)acc[mi][ni][r];
      }
  __syncthreads();

  // in-LDS scan replay with fp32 carry-in; write x back as bf16
  {
    float hr = carry_r, hi = carry_i;
#pragma unroll 8
    for (int j = 0; j < LC; ++j) {
      int row = chl * 32 + j;
      int idx = row * 256 + SWZ(k >> 2, row) * 8 + ((2 * k) & 7);
      bf16x2_t v2 = *(const bf16x2_t*)&sT[idx];
      float t = fmaf(hr, cc, fmaf(-hi, sv, (float)v2[0]));
      hi      = fmaf(hr, sv, fmaf( hi, cc, (float)v2[1]));
      hr = t;
      bf16x2_t o; o[0] = (__bf16)hr; o[1] = (__bf16)hi;
      *(bf16x2_t*)&sT[idx] = o;
    }
    if (t0 == 4032 && chl == 1) {           // last panel of batch b: x[b, 4095]
      state_out[b * 256 + 2 * k]     = hr;
      state_out[b * 256 + 2 * k + 1] = hi;
    }
  }
  __syncthreads();

  // MFMA: Y = X @ C
#pragma unroll
  for (int mi = 0; mi < 4; ++mi)
#pragma unroll
    for (int ni = 0; ni < 4; ++ni)
#pragma unroll
      for (int r = 0; r < 4; ++r) acc[mi][ni][r] = 0.f;

#pragma unroll
  for (int kc8 = 0; kc8 < 8; ++kc8) {
    bf16x8_t af[4], bfr[4];
#pragma unroll
    for (int mi = 0; mi < 4; ++mi) {
      int row = mi * 16 + m_l;
      int c   = kc8 * 4 + quad;
      af[mi] = *(const bf16x8_t*)&sT[row * 256 + SWZ(c, row) * 8];
    }
#pragma unroll
    for (int ni = 0; ni < 4; ++ni) {
      int n = wave * 64 + ni * 16 + m_l;
      bfr[ni] = *(const bf16x8_t*)(CT + (size_t)n * 256 + kc8 * 32 + quad * 8);
    }
#pragma unroll
    for (int mi = 0; mi < 4; ++mi)
#pragma unroll
      for (int ni = 0; ni < 4; ++ni)
        acc[mi][ni] = __builtin_amdgcn_mfma_f32_16x16x32_bf16(af[mi], bfr[ni], acc[mi][ni], 0, 0, 0);
  }

#pragma unroll
  for (int mi = 0; mi < 4; ++mi)
#pragma unroll
    for (int ni = 0; ni < 4; ++ni)
#pragma unroll
      for (int r = 0; r < 4; ++r) {
        int row = m0 + mi * 16 + quad * 4 + r;
        int col = wave * 64 + ni * 16 + m_l;
        Y[(size_t)row * 256 + col] = acc[mi][ni][r];
      }
}

extern "C" void kernel_launch(void* const* d_in, const int* in_sizes, int n_in,
                              void* d_out, int out_size, void* d_ws, size_t ws_size,
                              hipStream_t stream) {
  const float* u  = (const float*)d_in[0];
  const float* x0 = (const float*)d_in[1];
  const float* A  = (const float*)d_in[2];
  const float* B  = (const float*)d_in[3];
  const float* C  = (const float*)d_in[4];

  float* y         = (float*)d_out;
  float* state_out = y + (size_t)MTOT * 256;

  char* ws = (char*)d_ws;
  __bf16* BT = (__bf16*)ws;  ws += 256 * 256 * 2;
  __bf16* CT = (__bf16*)ws;  ws += 256 * 256 * 2;
  float2* P  = (float2*)ws;  ws += (size_t)BATCH * NCHUNK * KHALF * sizeof(float2);

  transpose_bc<<<dim3(256, 2), 256, 0, stream>>>(B, C, BT, CT);
  gemm_p<<<dim3(MTOT / 64), 256, 0, stream>>>(u, BT, A, P);
  ssm_out<<<dim3(MTOT / 64), 256, 0, stream>>>(u, BT, CT, A, x0, P, state_out, y);
}

// Round 6
// 122.255 us; speedup vs baseline: 1.0568x; 1.0568x over previous
//
#include <hip/hip_runtime.h>
#include <hip/hip_bf16.h>

typedef __bf16 bf16x2_t __attribute__((ext_vector_type(2)));
typedef __bf16 bf16x8_t __attribute__((ext_vector_type(8)));
typedef float f32x4 __attribute__((ext_vector_type(4)));

#define BATCH   8
#define LENGTH  4096
#define KHALF   128
#define MTOT    (BATCH*LENGTH)
#define NCHUNK  128
#define LC      32

// 16B-chunk XOR swizzle: chunk index ^ (row & 7). Keeps b128 frag reads and
// bf16x2 scan accesses at <=2-way bank conflict with ZERO padding.
#define SWZ(ch, row) ((ch) ^ ((row) & 7))

// ---------------- transpose B, C to bf16 ----------------
__global__ __launch_bounds__(256) void transpose_bc(
    const float* __restrict__ Bsrc, const float* __restrict__ Csrc,
    __bf16* __restrict__ BT, __bf16* __restrict__ CT) {
  const float* src = blockIdx.y ? Csrc : Bsrc;
  __bf16* dst      = blockIdx.y ? CT   : BT;
  int n  = blockIdx.x;
  int kk = threadIdx.x;
  dst[n * 256 + kk] = (__bf16)src[kk * 256 + n];
}

// ---------------- GEMM1: uB = u @ B (64x256 tile, full N), fused chunk-partial scan ----
__global__ __launch_bounds__(256, 3) void gemm1_fused(
    const float* __restrict__ u, const __bf16* __restrict__ BT,
    const float* __restrict__ Aarr,
    __bf16* __restrict__ uB, float2* __restrict__ P) {
  __shared__ __align__(16) __bf16 sA[64 * 256];   // 32 KB

  const int tid  = threadIdx.x;
  const int lane = tid & 63;
  const int wave = tid >> 6;          // column group (0..3)
  const int m_l  = lane & 15, quad = lane >> 4;
  const int m0   = blockIdx.x * 64;
  const int b    = m0 >> 12;
  const int t0   = m0 & 4095;

  // stage u (fp32 -> bf16), swizzled 16B chunks
#pragma unroll
  for (int i = 0; i < 8; ++i) {
    int s   = tid + i * 256;          // 0..2047 chunks of 8 cols
    int row = s >> 5, ch = s & 31;
    const float4* g = (const float4*)(u + (size_t)(m0 + row) * 256 + ch * 8);
    float4 a = g[0], c = g[1];
    bf16x8_t v;
    v[0]=(__bf16)a.x; v[1]=(__bf16)a.y; v[2]=(__bf16)a.z; v[3]=(__bf16)a.w;
    v[4]=(__bf16)c.x; v[5]=(__bf16)c.y; v[6]=(__bf16)c.z; v[7]=(__bf16)c.w;
    *(bf16x8_t*)&sA[row * 256 + SWZ(ch, row) * 8] = v;
  }
  __syncthreads();

  f32x4 acc[4][4];
#pragma unroll
  for (int mi = 0; mi < 4; ++mi)
#pragma unroll
    for (int ni = 0; ni < 4; ++ni)
#pragma unroll
      for (int r = 0; r < 4; ++r) acc[mi][ni][r] = 0.f;

#pragma unroll
  for (int kc8 = 0; kc8 < 8; ++kc8) {     // NO barriers in K-loop
    bf16x8_t af[4], bfr[4];
#pragma unroll
    for (int mi = 0; mi < 4; ++mi) {
      int row = mi * 16 + m_l;
      int c   = kc8 * 4 + quad;
      af[mi] = *(const bf16x8_t*)&sA[row * 256 + SWZ(c, row) * 8];
    }
#pragma unroll
    for (int ni = 0; ni < 4; ++ni) {
      int n = wave * 64 + ni * 16 + m_l;
      bfr[ni] = *(const bf16x8_t*)(BT + (size_t)n * 256 + kc8 * 32 + quad * 8);
    }
#pragma unroll
    for (int mi = 0; mi < 4; ++mi)
#pragma unroll
      for (int ni = 0; ni < 4; ++ni)
        acc[mi][ni] = __builtin_amdgcn_mfma_f32_16x16x32_bf16(af[mi], bfr[ni], acc[mi][ni], 0, 0, 0);
  }
  __syncthreads();   // done reading sA; reuse as output stash

  // stash bf16 64x256 tile into LDS (swizzled)
  __bf16* sT = sA;
#pragma unroll
  for (int mi = 0; mi < 4; ++mi)
#pragma unroll
    for (int ni = 0; ni < 4; ++ni)
#pragma unroll
      for (int r = 0; r < 4; ++r) {
        int row = mi * 16 + quad * 4 + r;
        int col = wave * 64 + ni * 16 + m_l;
        sT[row * 256 + SWZ(col >> 3, row) * 8 + (col & 7)] = (__bf16)acc[mi][ni][r];
      }
  __syncthreads();

  // coalesced uB write from LDS
#pragma unroll
  for (int i = 0; i < 8; ++i) {
    int s   = tid + i * 256;
    int row = s >> 5, ch = s & 31;
    *(bf16x8_t*)(uB + (size_t)(m0 + row) * 256 + ch * 8) =
        *(const bf16x8_t*)&sT[row * 256 + SWZ(ch, row) * 8];
  }

  // fused scan_partial: 2 chunks x 128 complex states = 256 scans, one per thread
  {
    int k   = tid & 127;
    int chl = tid >> 7;               // 0..1
    float cc = Aarr[4 * k], sv = Aarr[4 * k + 1];
    float hr = 0.f, hi = 0.f;
#pragma unroll 8
    for (int j = 0; j < LC; ++j) {
      int row = chl * 32 + j;
      bf16x2_t v2 = *(const bf16x2_t*)&sT[row * 256 + SWZ(k >> 2, row) * 8 + ((2 * k) & 7)];
      float t = fmaf(hr, cc, fmaf(-hi, sv, (float)v2[0]));
      hi      = fmaf(hr, sv, fmaf( hi, cc, (float)v2[1]));
      hr = t;
    }
    int chg = (t0 >> 5) + chl;
    P[((size_t)b * NCHUNK + chg) * KHALF + k] = make_float2(hr, hi);
  }
}

// ---------------- wave-parallel carry: one wave per (b,k), Kogge-Stone ----------------
__global__ __launch_bounds__(256) void scan_carry2(
    const float* __restrict__ Aarr, const float* __restrict__ x0,
    const float2* __restrict__ P, float2* __restrict__ H,
    float* __restrict__ state_out) {
  const int lane = threadIdx.x & 63;
  const int wv   = threadIdx.x >> 6;
  const int p    = blockIdx.x * 4 + wv;   // 0..1023 (b,k) pairs
  const int b    = p >> 7, k = p & 127;
  const float cc = Aarr[4 * k], sv = Aarr[4 * k + 1];

  // w32 = w^32 via 5 squarings
  float wr = cc, wi = sv;
#pragma unroll
  for (int i = 0; i < 5; ++i) { float nr = wr*wr - wi*wi; wi = 2.f*wr*wi; wr = nr; }
  // W[s] = w64^(2^s), s=0..5
  float Wr[6], Wi[6];
  Wr[0] = wr*wr - wi*wi; Wi[0] = 2.f*wr*wi;
#pragma unroll
  for (int s = 1; s < 6; ++s) { Wr[s] = Wr[s-1]*Wr[s-1] - Wi[s-1]*Wi[s-1]; Wi[s] = 2.f*Wr[s-1]*Wi[s-1]; }

  float2 P0 = P[((size_t)b * NCHUNK + 2 * lane)     * KHALF + k];
  float2 P1 = P[((size_t)b * NCHUNK + 2 * lane + 1) * KHALF + k];
  // pair combine: q = w32*P0 + P1  (segment scale w64)
  float qr = fmaf(wr, P0.x, fmaf(-wi, P0.y, P1.x));
  float qi = fmaf(wr, P0.y, fmaf( wi, P0.x, P1.y));
  // inclusive scan over lanes
  float Sr = qr, Si = qi;
#pragma unroll
  for (int s = 0; s < 6; ++s) {
    float tr = __shfl_up(Sr, 1 << s, 64);
    float ti = __shfl_up(Si, 1 << s, 64);
    if (lane >= (1 << s)) {
      float nSr = fmaf(Wr[s], tr, fmaf(-Wi[s], ti, Sr));
      float nSi = fmaf(Wr[s], ti, fmaf( Wi[s], tr, Si));
      Sr = nSr; Si = nSi;
    }
  }
  float Ar = __shfl_up(Sr, 1, 64), Ai = __shfl_up(Si, 1, 64);
  if (lane == 0) { Ar = 0.f; Ai = 0.f; }
  // pL = w64^lane
  float pr = 1.f, pi = 0.f;
#pragma unroll
  for (int s = 0; s < 6; ++s)
    if ((lane >> s) & 1) { float nr = pr*Wr[s] - pi*Wi[s]; pi = pr*Wi[s] + pi*Wr[s]; pr = nr; }

  float x0r = x0[b * 256 + 2 * k], x0i = x0[b * 256 + 2 * k + 1];
  float H0r = fmaf(pr, x0r, fmaf(-pi, x0i, Ar));
  float H0i = fmaf(pr, x0i, fmaf( pi, x0r, Ai));
  H[((size_t)b * NCHUNK + 2 * lane) * KHALF + k] = make_float2(H0r, H0i);
  float H1r = fmaf(wr, H0r, fmaf(-wi, H0i, P0.x));
  float H1i = fmaf(wr, H0i, fmaf( wi, H0r, P0.y));
  H[((size_t)b * NCHUNK + 2 * lane + 1) * KHALF + k] = make_float2(H1r, H1i);
  if (lane == 63) {
    state_out[b * 256 + 2 * k]     = fmaf(wr, H1r, fmaf(-wi, H1i, P1.x));
    state_out[b * 256 + 2 * k + 1] = fmaf(wr, H1i, fmaf( wi, H1r, P1.y));
  }
}

// ---------------- GEMM2: y = X @ C (64x256 tile, full N), X replayed in-LDS ------------
__global__ __launch_bounds__(256, 3) void gemm2_fused(
    const __bf16* __restrict__ uB, const float* __restrict__ Aarr,
    const float2* __restrict__ H, const __bf16* __restrict__ CT,
    float* __restrict__ Y) {
  __shared__ __align__(16) __bf16 sX[64 * 256];   // 32 KB

  const int tid  = threadIdx.x;
  const int lane = tid & 63;
  const int wave = tid >> 6;
  const int m_l  = lane & 15, quad = lane >> 4;
  const int m0   = blockIdx.x * 64;
  const int b    = m0 >> 12;
  const int t0   = m0 & 4095;

  // stage uB -> sX (swizzled), uB read exactly once
#pragma unroll
  for (int i = 0; i < 8; ++i) {
    int s   = tid + i * 256;
    int row = s >> 5, ch = s & 31;
    *(bf16x8_t*)&sX[row * 256 + SWZ(ch, row) * 8] =
        *(const bf16x8_t*)(uB + (size_t)(m0 + row) * 256 + ch * 8);
  }
  __syncthreads();

  // in-LDS scan replay: 2 chunks x 128 k = 256 scans, one per thread (disjoint RMW)
  {
    int k   = tid & 127;
    int chl = tid >> 7;
    float cc = Aarr[4 * k], sv = Aarr[4 * k + 1];
    float2 h = H[((size_t)b * NCHUNK + (t0 >> 5) + chl) * KHALF + k];
    float hr = h.x, hi = h.y;
#pragma unroll 8
    for (int j = 0; j < LC; ++j) {
      int row = chl * 32 + j;
      int idx = row * 256 + SWZ(k >> 2, row) * 8 + ((2 * k) & 7);
      bf16x2_t v2 = *(const bf16x2_t*)&sX[idx];
      float t = fmaf(hr, cc, fmaf(-hi, sv, (float)v2[0]));
      hi      = fmaf(hr, sv, fmaf( hi, cc, (float)v2[1]));
      hr = t;
      bf16x2_t o; o[0] = (__bf16)hr; o[1] = (__bf16)hi;
      *(bf16x2_t*)&sX[idx] = o;
    }
  }
  __syncthreads();

  f32x4 acc[4][4];
#pragma unroll
  for (int mi = 0; mi < 4; ++mi)
#pragma unroll
    for (int ni = 0; ni < 4; ++ni)
#pragma unroll
      for (int r = 0; r < 4; ++r) acc[mi][ni][r] = 0.f;

#pragma unroll
  for (int kc8 = 0; kc8 < 8; ++kc8) {     // barrier-free K-loop
    bf16x8_t af[4], bfr[4];
#pragma unroll
    for (int mi = 0; mi < 4; ++mi) {
      int row = mi * 16 + m_l;
      int c   = kc8 * 4 + quad;
      af[mi] = *(const bf16x8_t*)&sX[row * 256 + SWZ(c, row) * 8];
    }
#pragma unroll
    for (int ni = 0; ni < 4; ++ni) {
      int n = wave * 64 + ni * 16 + m_l;
      bfr[ni] = *(const bf16x8_t*)(CT + (size_t)n * 256 + kc8 * 32 + quad * 8);
    }
#pragma unroll
    for (int mi = 0; mi < 4; ++mi)
#pragma unroll
      for (int ni = 0; ni < 4; ++ni)
        acc[mi][ni] = __builtin_amdgcn_mfma_f32_16x16x32_bf16(af[mi], bfr[ni], acc[mi][ni], 0, 0, 0);
  }

  // streaming fp32 output: non-temporal to keep BT/CT/uB in L2
#pragma unroll
  for (int mi = 0; mi < 4; ++mi)
#pragma unroll
    for (int ni = 0; ni < 4; ++ni)
#pragma unroll
      for (int r = 0; r < 4; ++r) {
        int row = m0 + mi * 16 + quad * 4 + r;
        int col = wave * 64 + ni * 16 + m_l;
        __builtin_nontemporal_store(acc[mi][ni][r], &Y[(size_t)row * 256 + col]);
      }
}

extern "C" void kernel_launch(void* const* d_in, const int* in_sizes, int n_in,
                              void* d_out, int out_size, void* d_ws, size_t ws_size,
                              hipStream_t stream) {
  const float* u  = (const float*)d_in[0];
  const float* x0 = (const float*)d_in[1];
  const float* A  = (const float*)d_in[2];
  const float* B  = (const float*)d_in[3];
  const float* C  = (const float*)d_in[4];

  float* y         = (float*)d_out;
  float* state_out = y + (size_t)MTOT * 256;

  char* ws = (char*)d_ws;
  __bf16* BT = (__bf16*)ws;  ws += 256 * 256 * 2;
  __bf16* CT = (__bf16*)ws;  ws += 256 * 256 * 2;
  __bf16* uB = (__bf16*)ws;  ws += (size_t)MTOT * 256 * 2;
  float2* P  = (float2*)ws;  ws += (size_t)BATCH * NCHUNK * KHALF * sizeof(float2);
  float2* H  = (float2*)ws;  ws += (size_t)BATCH * NCHUNK * KHALF * sizeof(float2);

  transpose_bc<<<dim3(256, 2), 256, 0, stream>>>(B, C, BT, CT);
  gemm1_fused<<<dim3(MTOT / 64), 256, 0, stream>>>(u, BT, A, uB, P);
  scan_carry2<<<dim3(256), 256, 0, stream>>>(A, x0, P, H, state_out);
  gemm2_fused<<<dim3(MTOT / 64), 256, 0, stream>>>(uB, A, H, CT, y);
}